// Round 13
// baseline (73.160 us; speedup 1.0000x reference)
//
#include <hip/hip_runtime.h>
#include <math.h>

// LongRangeProj forward, MI355X. B=2,C=64,NH=NW=8,H=W=64,STRIDE=8.
// term(n,p) = A + B*fn + C0*fn^2 + C1*ang^2,  out = exp(max_n term)
//   A = ln x - rm^2*inv2rs, B = 2*rm*inv2rs (per plane,node -> LDS)
//   C0 = -inv2rs, C1 = -inv2as (per plane -> regs)
//   ang^2 = d^2 + min(0, 4pi^2 - 4pi*|d|), d = phi - theta_wrapped
// Geometry tab4[dyi][jp][wpx] (float4 = {fn,phi} for j=2jp,2jp+1), 491 KB,
// REPLICATED x8 so each XCD reads its own L2-local copy (blockIdx%8 == XCD
// round-robin heuristic; perf-only). One block = 256 pixels x 4 planes:
// each dwordx4 covers 2 terms x 4 planes. All 32 loads prefetched
// (launch_bounds(256,2), ~180 VGPR) to maximize miss-level parallelism.
// Mask point (dx=dy=0): in-loop value <= A; center-pixel epilogue fmax.

#define TWO_PI_F   6.28318530717958647692f
#define INV_2PI_F  0.15915494309189533577f
#define FOUR_PI_F  12.56637061435917295385f
#define FOUR_PI2_F 39.47841760435743447534f
#define REPL_STRIDE 30720   // elements per replica (120*4*64)

__global__ __launch_bounds__(256) void lrp_geom(float4* __restrict__ tab4)
{
    const int r    = blockIdx.x & 7;        // replica (targets XCD r)
    const int idx  = (blockIdx.x >> 3) * 256 + threadIdx.x;  // 0..30719
    const int wpx = idx & 63;
    const int jp  = (idx >> 6) & 3;
    const int dyi = idx >> 8;                               // 0..119
    const float dy  = (float)(dyi - 56);
    const float dxa = (float)(wpx - 16 * jp);               // j = 2*jp
    const float dxb = dxa - 8.0f;                           // j = 2*jp+1
    const float fna = sqrtf(fmaf(dxa, dxa, dy * dy));
    const float fnb = sqrtf(fmaf(dxb, dxb, dy * dy));
    const float pha = atan2f(dy, dxa);                      // setup only
    const float phb = atan2f(dy, dxb);
    tab4[r * REPL_STRIDE + idx] = make_float4(fna, pha, fnb, phb);
}

__global__ __launch_bounds__(256, 2) void lrp_fwd(
    const float* __restrict__ x,
    const float* __restrict__ rmean,
    const float* __restrict__ amean,
    const float* __restrict__ rstd,
    const float* __restrict__ astd,
    const float4* __restrict__ tab4,
    float* __restrict__ out)
{
    __shared__ float4 prm[4][64];   // {A, B, theta_w, 0} per (plane, node)
    __shared__ float2 cst[4];       // {C0, C1} per plane

    const int tid  = threadIdx.x;
    const int pg   = blockIdx.x >> 4;     // plane group 0..31 (4 planes each)
    const int tile = blockIdx.x & 15;     // 256-pixel tile
    const int bc0  = pg * 4;
    const int rep  = blockIdx.x & 7;      // XCD-local table replica

    {   // one thread per (plane, node)
        const int p  = tid >> 6;
        const int n  = tid & 63;
        const int bc = bc0 + p;
        const int c  = bc & 63;
        const float rs = rstd[c];
        const float as = astd[c];
        const float inv2rs = 1.0f / (2.0f * fmaf(rs, rs, 0.01f));
        const float inv2as = 1.0f / (2.0f * fmaf(as, as, 1e-4f));
        const int idx = bc * 64 + n;
        const float lx = logf(x[idx]);
        const float rm = fabsf(rmean[idx]);
        float th = amean[idx];
        th = fmaf(__builtin_rintf(th * INV_2PI_F), -TWO_PI_F, th); // [-pi,pi]
        prm[p][n] = make_float4(fmaf(-(rm * rm), inv2rs, lx),
                                2.0f * rm * inv2rs, th, 0.0f);
        if (n == 0) cst[p] = make_float2(-inv2rs, -inv2as);
    }

    __syncthreads();

    const int pp  = tile * 256 + tid;   // pixel in plane, 0..4095
    const int wpx = pp & 63;
    const int hpx = pp >> 6;

    const float4* base = tab4 + (rep * REPL_STRIDE + wpx);

    // Prefetch all 32 geometry quads (static indices -> registers).
    float4 g[8][4];
    #pragma unroll
    for (int i = 0; i < 8; ++i) {
        const float4* rowp = base + (hpx + 56 - 8 * i) * 256;
        #pragma unroll
        for (int jp = 0; jp < 4; ++jp) g[i][jp] = rowp[jp * 64];
    }

    const float2 c0 = cst[0], c1 = cst[1], c2 = cst[2], c3 = cst[3];
    const float C0[4] = {c0.x, c1.x, c2.x, c3.x};
    const float C1[4] = {c0.y, c1.y, c2.y, c3.y};

    float acc[4] = {-INFINITY, -INFINITY, -INFINITY, -INFINITY};

    #pragma unroll
    for (int i = 0; i < 8; ++i) {
        #pragma unroll
        for (int jp = 0; jp < 4; ++jp) {
            const float4 gg = g[i][jp];
            const int    na = i * 8 + 2 * jp;
            #pragma unroll
            for (int p = 0; p < 4; ++p) {
                const float4 qa = prm[p][na];       // LDS broadcast
                const float4 qb = prm[p][na + 1];
                {   // term a: fn=gg.x, phi=gg.y
                    const float d  = gg.y - qa.z;
                    const float aa = fmaf(d, d,
                        fminf(0.0f, fmaf(-FOUR_PI_F, fabsf(d), FOUR_PI2_F)));
                    const float mid = fmaf(gg.x, fmaf(gg.x, C0[p], qa.y), qa.x);
                    acc[p] = fmaxf(acc[p], fmaf(aa, C1[p], mid));
                }
                {   // term b: fn=gg.z, phi=gg.w
                    const float d  = gg.w - qb.z;
                    const float aa = fmaf(d, d,
                        fminf(0.0f, fmaf(-FOUR_PI_F, fabsf(d), FOUR_PI2_F)));
                    const float mid = fmaf(gg.z, fmaf(gg.z, C0[p], qb.y), qb.x);
                    acc[p] = fmaxf(acc[p], fmaf(aa, C1[p], mid));
                }
            }
        }
    }

    // Mask-point epilogue: center pixel's own-node term is exactly A and
    // dominates the unfixed in-loop value.
    if (((wpx & 7) | (hpx & 7)) == 0) {
        const int ni = (hpx >> 3) * 8 + (wpx >> 3);
        #pragma unroll
        for (int p = 0; p < 4; ++p)
            acc[p] = fmaxf(acc[p], prm[p][ni].x);
    }

    #pragma unroll
    for (int p = 0; p < 4; ++p)
        out[(bc0 + p) * 4096 + pp] = __expf(acc[p]);
}

extern "C" void kernel_launch(void* const* d_in, const int* in_sizes, int n_in,
                              void* d_out, int out_size, void* d_ws, size_t ws_size,
                              hipStream_t stream) {
    const float* x     = (const float*)d_in[0];
    const float* rmean = (const float*)d_in[1];
    const float* amean = (const float*)d_in[2];
    const float* rstd  = (const float*)d_in[3];
    const float* astd  = (const float*)d_in[4];
    float* out  = (float*)d_out;
    float4* tab4 = (float4*)d_ws;       // 8 replicas x 491.5 KB = 3.93 MB

    lrp_geom<<<960, 256, 0, stream>>>(tab4);   // replica r from blocks %8==r
    // 32 plane-groups x 16 tiles = 512 blocks; 2 blocks/CU; 4 planes/block.
    lrp_fwd<<<512, 256, 0, stream>>>(x, rmean, amean, rstd, astd, tab4, out);
}